// Round 2
// 312.377 us; speedup vs baseline: 1.0385x; 1.0385x over previous
//
#include <hip/hip_runtime.h>
#include <math.h>

#define EPS 1e-8f

typedef float vfloat4 __attribute__((ext_vector_type(4)));

// ---------------- prep kernel (fused transpose + Gram) ----------------
// blocks 0..383   : transpose W_enc [24][1024] -> wt [1024][24]  (64 thr each)
// blocks 384..959 : G[l][m] = sum_d Wd[d][l]*Wd[d][m]
// blocks 960..983 : h[l] = sum_d Wd[d][l]*bd[d]
// block  984      : bb = ||bd||^2
__global__ void prep_all(const float* __restrict__ W_enc,
                         const float* __restrict__ Wd, const float* __restrict__ bd,
                         float* __restrict__ wt, float* __restrict__ G,
                         float* __restrict__ h, float* __restrict__ bb) {
    int b = blockIdx.x;
    int lane = threadIdx.x;     // 64
    if (b < 384) {
        int i = b * 64 + lane;  // 0..24575
        int k = i / 24, l = i - k * 24;
        wt[i] = W_enc[l * 1024 + k];
        return;
    }
    b -= 384;
    float s = 0.f;
    if (b < 576) {
        int l = b / 24, m = b - (b / 24) * 24;
        for (int d = lane; d < 1024; d += 64) s = fmaf(Wd[d * 24 + l], Wd[d * 24 + m], s);
    } else if (b < 600) {
        int l = b - 576;
        for (int d = lane; d < 1024; d += 64) s = fmaf(Wd[d * 24 + l], bd[d], s);
    } else {
        for (int d = lane; d < 1024; d += 64) s = fmaf(bd[d], bd[d], s);
    }
    for (int off = 32; off; off >>= 1) s += __shfl_down(s, off);
    if (lane == 0) {
        if (b < 576) G[b] = s;
        else if (b < 600) h[b - 576] = s;
        else *bb = s;
    }
}

// ---------------- main kernel ----------------
// Block = 512 threads (8 waves), 64 rows per block, lane = row.
// Wave w owns k-range [128w,128w+128) (encode) and same d-range (decode).
// Grid = 512 blocks -> 2 blocks/CU x 8 waves = 16 waves/CU (was 8).
// Tiles are WAVE-PRIVATE: same-wave LDS ops are in-order -> no barriers in
// the chunk loops. Exactly 2 __syncthreads (around the cross-wave combine).
// LDS tile uses XOR swizzle (col ^ (row&31)) instead of +1 pad so that
// 8 tiles fit in exactly 64 KB: scalar reads at common kk across 64 lanes
// are 2 lanes/bank (free), staged writes are 2-way as well.
// Combine scratch (25x64 floats/wave) overlays the wave's OWN tile region.

constexpr int LD_TILE = 32;            // XOR-swizzled, no pad
constexpr int TILE_F  = 64 * LD_TILE;  // 2048 floats per wave
constexpr int NW      = 8;
constexpr int SMEM_F  = NW * TILE_F;   // 16384 floats = 65536 B -> 2 blocks/CU

__global__ __launch_bounds__(512, 4)
void leech_main(const float* __restrict__ data,
                const float* __restrict__ b_enc,
                const float* __restrict__ Wd,
                const float* __restrict__ b_dec,
                const float* __restrict__ ecs_p,
                const float* __restrict__ ep_p,
                const float* __restrict__ wt,
                const float* __restrict__ G,
                const float* __restrict__ h,
                const float* __restrict__ bbp,
                float* __restrict__ out)
{
    __shared__ float smem[SMEM_F];
    const int tid = threadIdx.x;
    const int w = tid >> 6;         // 0..7
    const int r = tid & 63;
    const int rowbase = blockIdx.x * 64;

    float* tile = smem + w * TILE_F;

    const int lrow = r >> 3;        // 0..7
    const int lk   = (r & 7) * 4;   // 0,4,...,28

    // -------- encode: proj partials over this wave's 128-wide k-range --------
    float proj[24];
#pragma unroll
    for (int l = 0; l < 24; ++l) proj[l] = 0.f;
    float ssq = 0.f;

    const int kw = __builtin_amdgcn_readfirstlane((tid >> 6) * 128);

    float4 buf[8];
#pragma unroll
    for (int it = 0; it < 8; ++it)
        buf[it] = *reinterpret_cast<const float4*>(
            data + (size_t)(rowbase + it * 8 + lrow) * 1024 + kw + lk);

    for (int sc = 0; sc < 4; ++sc) {
        // stage current chunk into wave-private swizzled tile
#pragma unroll
        for (int it = 0; it < 8; ++it) {
            const int row = it * 8 + lrow;
            const int rb = row & 31;
            float* t = tile + row * LD_TILE;
            t[(lk + 0) ^ rb] = buf[it].x;
            t[(lk + 1) ^ rb] = buf[it].y;
            t[(lk + 2) ^ rb] = buf[it].z;
            t[(lk + 3) ^ rb] = buf[it].w;
        }
        // prefetch next chunk (issued before compute; latency hidden)
        if (sc < 3) {
            const int k0n = kw + (sc + 1) * 32;
#pragma unroll
            for (int it = 0; it < 8; ++it)
                buf[it] = *reinterpret_cast<const float4*>(
                    data + (size_t)(rowbase + it * 8 + lrow) * 1024 + k0n + lk);
        }
        // compute on current chunk (same-wave LDS in-order: no barrier)
        const float* xrow = tile + r * LD_TILE;
        const int rb = r & 31;
        const int kofs = __builtin_amdgcn_readfirstlane(kw + sc * 32);
#pragma unroll 8
        for (int kk = 0; kk < 32; ++kk) {
            const float x = xrow[kk ^ rb];
            ssq = fmaf(x, x, ssq);
            const float* wp = wt + (size_t)(kofs + kk) * 24;   // uniform -> s_load
#pragma unroll
            for (int l = 0; l < 24; ++l)
                proj[l] = fmaf(wp[l], x, proj[l]);
        }
    }

    // -------- combine partials across the 8 waves (overlay own tile) --------
#pragma unroll
    for (int l = 0; l < 24; ++l)
        smem[w * TILE_F + l * 64 + r] = proj[l];
    smem[w * TILE_F + 24 * 64 + r] = ssq;
    __syncthreads();

    float p[24];
#pragma unroll
    for (int l = 0; l < 24; ++l) {
        float s0 = smem[0 * TILE_F + l * 64 + r] + smem[1 * TILE_F + l * 64 + r];
        float s1 = smem[2 * TILE_F + l * 64 + r] + smem[3 * TILE_F + l * 64 + r];
        float s2 = smem[4 * TILE_F + l * 64 + r] + smem[5 * TILE_F + l * 64 + r];
        float s3 = smem[6 * TILE_F + l * 64 + r] + smem[7 * TILE_F + l * 64 + r];
        p[l] = (s0 + s1) + (s2 + s3);
    }
    float ss;
    {
        float s0 = smem[0 * TILE_F + 24 * 64 + r] + smem[1 * TILE_F + 24 * 64 + r];
        float s1 = smem[2 * TILE_F + 24 * 64 + r] + smem[3 * TILE_F + 24 * 64 + r];
        float s2 = smem[4 * TILE_F + 24 * 64 + r] + smem[5 * TILE_F + 24 * 64 + r];
        float s3 = smem[6 * TILE_F + 24 * 64 + r] + smem[7 * TILE_F + 24 * 64 + r];
        ss = (s0 + s1) + (s2 + s3);
    }
    __syncthreads();   // all combine reads done before decode overwrites tiles

    // -------- per-row epilogue --------
    const float ecs = ecs_p[0];
    const float ep  = ep_p[0];
    const float in_e = sqrtf(ss);

    float lp[24]; float oe = 0.f;
#pragma unroll
    for (int l = 0; l < 24; ++l) {
        const float pp = p[l] + b_enc[l];
        const float q = rintf(pp / ecs) * ecs;   // half-even, exact div to match np
        lp[l] = q;
        oe = fmaf(q, q, oe);
    }
    const float s1 = in_e / (sqrtf(oe) + EPS) * ep;

    float c[24]; float ie = 0.f;
#pragma unroll
    for (int l = 0; l < 24; ++l) {
        const float lat = lp[l] * s1;
        ie = fmaf(lat, lat, ie);
        c[l] = (fabsf(lat) > ecs) ? lat : 0.f;
    }
    const float in_e2 = sqrtf(ie);

    // ||Wd c + b_dec||^2 = c^T G c + 2 h^T c + bb
    float qacc = bbp[0];
#pragma unroll
    for (int l = 0; l < 24; ++l) {
        float s = 2.f * h[l];
#pragma unroll
        for (int m = 0; m < 24; ++m)
            s = fmaf(G[l * 24 + m], c[m], s);
        qacc = fmaf(s, c[l], qacc);
    }
    const float out_e2 = sqrtf(fmaxf(qacc, 0.f));
    const float s2 = in_e2 / (out_e2 + EPS) * ep;

    // -------- decode: wave-private swizzled transpose tiles, no barriers ----
    for (int sc = 0; sc < 4; ++sc) {
        const int d0 = __builtin_amdgcn_readfirstlane(kw + sc * 32);
        float* trow = tile + r * LD_TILE;
        const int rb = r & 31;
#pragma unroll 4
        for (int dd = 0; dd < 32; ++dd) {
            const int d = d0 + dd;
            const float* wr = Wd + d * 24;       // uniform -> s_load
            float acc = b_dec[d];
#pragma unroll
            for (int l = 0; l < 24; ++l)
                acc = fmaf(wr[l], c[l], acc);
            trow[dd ^ rb] = acc * s2;
        }
        // same-wave LDS in-order: reads below see this wave's writes above
#pragma unroll
        for (int it = 0; it < 8; ++it) {
            const int row = it * 8 + lrow;
            const int rb2 = row & 31;
            const float* t = tile + row * LD_TILE;
            vfloat4 v;
            v.x = t[(lk + 0) ^ rb2];
            v.y = t[(lk + 1) ^ rb2];
            v.z = t[(lk + 2) ^ rb2];
            v.w = t[(lk + 3) ^ rb2];
            __builtin_nontemporal_store(v, reinterpret_cast<vfloat4*>(
                out + (size_t)(rowbase + row) * 1024 + d0 + lk));
        }
    }
}

// ---------------- launcher ----------------

extern "C" void kernel_launch(void* const* d_in, const int* in_sizes, int n_in,
                              void* d_out, int out_size, void* d_ws, size_t ws_size,
                              hipStream_t stream) {
    const float* data  = (const float*)d_in[0];
    const float* W_enc = (const float*)d_in[1];
    const float* b_enc = (const float*)d_in[2];
    const float* W_dec = (const float*)d_in[3];
    const float* b_dec = (const float*)d_in[4];
    const float* ecs   = (const float*)d_in[5];
    const float* ep    = (const float*)d_in[6];
    float* out = (float*)d_out;

    float* ws = (float*)d_ws;
    float* wt = ws;                 // 24576 floats: W_enc transposed, k-major
    float* G  = ws + 24576;         // 576
    float* h  = ws + 25152;         // 24
    float* bb = ws + 25176;         // 1

    const int rows = in_sizes[0] / 1024;    // 32768

    hipLaunchKernelGGL(prep_all, dim3(985), dim3(64), 0, stream,
                       W_enc, W_dec, b_dec, wt, G, h, bb);
    hipLaunchKernelGGL(leech_main, dim3(rows / 64), dim3(512), 0, stream,
                       data, b_enc, W_dec, b_dec, ecs, ep, wt, G, h, bb, out);
}